// Round 3
// baseline (271.929 us; speedup 1.0000x reference)
//
#include <hip/hip_runtime.h>
#include <hip/hip_fp16.h>
#include <math.h>

#define N_NODES   50000
#define N_EDGES   800000
#define IN_DIM    128
#define HID       64
#define OUT_DIM   128
#define N_GRAPHS  256
#define MAX_DEG   64      // ELL row stride; P(indeg>64) for Binomial(800k,1/50k) ~ 0
#define PARTS     8       // XCD count; blockIdx%8 -> XCD round-robin heuristic
#define PSIZE     (N_NODES / PARTS)
#define EPB       4096    // edges per build chunk (= 256 threads x 16 edges)
#define AGG_NPB   64      // nodes per agg block (4 waves x 16 quads)
#define PSTRIDE   ((size_t)N_NODES * 32)   // halves per feature plane

typedef _Float16 half8 __attribute__((ext_vector_type(8)));
typedef float floatx4 __attribute__((ext_vector_type(4)));
typedef unsigned int uintx4 __attribute__((ext_vector_type(4)));  // native vec for nontemporal builtins

// ---------------- preprocessing ----------------

// XCD-partitioned histogram + ELL fill.
// R6: force MLP — batch-load 16 edges via int4, atomic pass, then store pass.
__global__ __launch_bounds__(256) void k_build(const int* __restrict__ src,
                                               const int* __restrict__ dst,
                                               int* __restrict__ deg, int* __restrict__ col) {
    int p     = blockIdx.x & (PARTS - 1);
    int chunk = blockIdx.x >> 3;
    int e0    = chunk * EPB + threadIdx.x * 16;
    if (e0 + 16 > N_EDGES) return;        // tail chunk is 1280 = 80*16 edges: clean cut
    int lo = p * PSIZE, hi = lo + PSIZE;

    int dd[16], ss[16];
    const int4* d4 = (const int4*)(dst + e0);
    const int4* s4 = (const int4*)(src + e0);
#pragma unroll
    for (int j = 0; j < 4; j++) {
        int4 q = d4[j];
        dd[4 * j + 0] = q.x; dd[4 * j + 1] = q.y;
        dd[4 * j + 2] = q.z; dd[4 * j + 3] = q.w;
    }
#pragma unroll
    for (int j = 0; j < 4; j++) {
        int4 q = s4[j];
        ss[4 * j + 0] = q.x; ss[4 * j + 1] = q.y;
        ss[4 * j + 2] = q.z; ss[4 * j + 3] = q.w;
    }

    // phase 1: issue all matching atomics back-to-back (independent chains)
    int pos[16];
#pragma unroll
    for (int j = 0; j < 16; j++) {
        pos[j] = -1;
        if (dd[j] >= lo && dd[j] < hi) pos[j] = atomicAdd(&deg[dd[j]], 1);
    }
    // phase 2: scatter stores (each waits only on its own atomic return)
#pragma unroll
    for (int j = 0; j < 16; j++) {
        if (pos[j] >= 0 && pos[j] < MAX_DEG)
            col[(size_t)dd[j] * MAX_DEG + pos[j]] = ss[j];
    }
}

// merged: dinv (blocks 0..195) + pack W1 (196..199) + pack W2 (200..201)
__global__ __launch_bounds__(256) void k_prep(const int* __restrict__ deg,
                                              float* __restrict__ dinv,
                                              const float* __restrict__ W1, __half* __restrict__ Wt1,
                                              const float* __restrict__ W2, __half* __restrict__ Wt2) {
    int blk = blockIdx.x;
    if (blk < 196) {
        int n = blk * 256 + threadIdx.x;
        if (n < N_NODES) dinv[n] = rsqrtf((float)(deg[n] + 1));  // +1 self-loop
    } else if (blk < 200) {
        int idx = (blk - 196) * 256 + threadIdx.x;   // 0..1023 = (128/8)*64
        int g = idx >> 6, n = idx & 63;
#pragma unroll
        for (int i = 0; i < 8; i++)
            Wt1[idx * 8 + i] = __float2half(W1[(8 * g + i) * 64 + n]);
    } else {
        int idx = (blk - 200) * 256 + threadIdx.x;   // 0..511 = (64/8)*64
        if (idx < 512) {
            int g = idx >> 6, n = idx & 63;
#pragma unroll
            for (int i = 0; i < 8; i++)
                Wt2[idx * 8 + i] = __float2half(W2[(8 * g + i) * 64 + n]);
        }
    }
}

// ---------------- MFMA GEMM layer 1: C = (dinv ⊙ x_fp32) @ W1, plane-split store ----------------
// C layout: plane p (=col/32) at C + p*PSTRIDE, row-major [N][32] per plane.

__global__ __launch_bounds__(256) void k_mfma1(const float* __restrict__ A,
                                               const float* __restrict__ dinv,
                                               const __half* __restrict__ Bp,
                                               __half* __restrict__ C) {
    constexpr int K = IN_DIM, S = K / 32;
    int wv   = threadIdx.x >> 6;
    int lane = threadIdx.x & 63;
    int quad = lane >> 4, l15 = lane & 15;
    int row0 = blockIdx.x * 64 + wv * 16;
    if (row0 >= N_NODES) return;   // 50000 % 16 == 0

    half8 bf[S][4];
#pragma unroll
    for (int s = 0; s < S; s++)
#pragma unroll
        for (int j = 0; j < 4; j++)
            bf[s][j] = *(const half8*)(Bp + ((size_t)((4 * s + quad) * 64 + 16 * j + l15)) * 8);

    floatx4 acc[4];
#pragma unroll
    for (int j = 0; j < 4; j++) acc[j] = 0.f;

    int arow = row0 + l15;
    float dv = dinv[arow];
#pragma unroll
    for (int s = 0; s < S; s++) {
        float4 xa = *(const float4*)(A + (size_t)arow * K + 32 * s + quad * 8);
        float4 xb = *(const float4*)(A + (size_t)arow * K + 32 * s + quad * 8 + 4);
        half8 af;
        af[0] = (_Float16)(xa.x * dv); af[1] = (_Float16)(xa.y * dv);
        af[2] = (_Float16)(xa.z * dv); af[3] = (_Float16)(xa.w * dv);
        af[4] = (_Float16)(xb.x * dv); af[5] = (_Float16)(xb.y * dv);
        af[6] = (_Float16)(xb.z * dv); af[7] = (_Float16)(xb.w * dv);
#pragma unroll
        for (int j = 0; j < 4; j++)
            acc[j] = __builtin_amdgcn_mfma_f32_16x16x32_f16(af, bf[s][j], acc[j], 0, 0, 0);
    }
#pragma unroll
    for (int j = 0; j < 4; j++)
#pragma unroll
        for (int r = 0; r < 4; r++)
            C[(size_t)(j >> 1) * PSTRIDE + (size_t)(row0 + quad * 4 + r) * 32 +
              16 * (j & 1) + l15] = __float2half(acc[j][r]);
}

// ---------------- MFMA GEMM layer 2: fp16 A (plane-split load + store) ----------------

__global__ __launch_bounds__(256) void k_mfma2(const __half* __restrict__ A,
                                               const __half* __restrict__ Bp,
                                               __half* __restrict__ C) {
    constexpr int K = HID, S = K / 32;
    int wv   = threadIdx.x >> 6;
    int lane = threadIdx.x & 63;
    int quad = lane >> 4, l15 = lane & 15;
    int row0 = blockIdx.x * 64 + wv * 16;
    if (row0 >= N_NODES) return;

    half8 bf[S][4];
#pragma unroll
    for (int s = 0; s < S; s++)
#pragma unroll
        for (int j = 0; j < 4; j++)
            bf[s][j] = *(const half8*)(Bp + ((size_t)((4 * s + quad) * 64 + 16 * j + l15)) * 8);

    floatx4 acc[4];
#pragma unroll
    for (int j = 0; j < 4; j++) acc[j] = 0.f;

    int arow = row0 + l15;
#pragma unroll
    for (int s = 0; s < S; s++) {
        half8 af = *(const half8*)(A + (size_t)s * PSTRIDE + (size_t)arow * 32 + quad * 8);
#pragma unroll
        for (int j = 0; j < 4; j++)
            acc[j] = __builtin_amdgcn_mfma_f32_16x16x32_f16(af, bf[s][j], acc[j], 0, 0, 0);
    }
#pragma unroll
    for (int j = 0; j < 4; j++)
#pragma unroll
        for (int r = 0; r < 4; r++)
            C[(size_t)(j >> 1) * PSTRIDE + (size_t)(row0 + quad * 4 + r) * 32 +
              16 * (j & 1) + l15] = __float2half(acc[j][r]);
}

// ---------------- aggregation v5: plane-split gather (XCD-L2-resident table) ----------------
// grid = 2 * ceil(N/64); plane = blockIdx&1  (round-robin XCD map -> XCD parity == plane,
// so each XCD gathers from only ONE 3.2 MB plane -> fits its 4 MB L2).
// Per block: 64 nodes x 32 features. 4 waves x 16 quads; quad = node, t = 16B chunk of 64B half-row.
// mode 0: OUT = dinv * gelu_tanh( dinv*(Σ_in T[s] + T[d]) + b )   (pre-scaled for next layer)
// mode 1: OUT = dinv * (Σ_in T[s] + T[d])

__device__ __forceinline__ void add8(float* acc, uintx4 v) {
    const __half2* h = (const __half2*)&v;
#pragma unroll
    for (int j = 0; j < 4; j++) {
        acc[2 * j]     += __low2float(h[j]);
        acc[2 * j + 1] += __high2float(h[j]);
    }
}

__global__ __launch_bounds__(256) void k_agg(const __half* __restrict__ T,
                                             const int* __restrict__ col,
                                             const int* __restrict__ indeg,
                                             const float* __restrict__ dinv,
                                             const float* __restrict__ b,
                                             __half* __restrict__ OUT, int mode) {
    __shared__ int cols[AGG_NPB][MAX_DEG + 1];   // +1 pad: quads land in distinct banks
    __shared__ int sdeg[AGG_NPB];
    int plane = blockIdx.x & 1;
    int base  = (blockIdx.x >> 1) * AGG_NPB;

    if (threadIdx.x < AGG_NPB) {
        int g = base + threadIdx.x;
        int dg0 = (g < N_NODES) ? indeg[g] : 0;
        sdeg[threadIdx.x] = dg0 > MAX_DEG ? MAX_DEG : dg0;
    }
    __syncthreads();

    // stage only live ELL slots; nontemporal: don't evict the resident gather plane
    for (int idx = threadIdx.x; idx < AGG_NPB * MAX_DEG; idx += 256) {
        int r = idx >> 6, j = idx & 63;
        if (j < sdeg[r])
            cols[r][j] = __builtin_nontemporal_load(col + (size_t)(base + r) * MAX_DEG + j);
    }
    __syncthreads();

    int lane = threadIdx.x & 63;
    int wv   = threadIdx.x >> 6;
    int q = lane >> 2, t = lane & 3;     // quad = node, t = 16-byte chunk of the 64B half-row
    int local = wv * 16 + q;
    int d = base + local;
    if (d >= N_NODES) return;            // tail block: whole quads drop out

    int dg = sdeg[local];
    const __half* P = T + (size_t)plane * PSTRIDE;

    float acc[8];
#pragma unroll
    for (int j = 0; j < 8; j++) acc[j] = 0.f;
    add8(acc, *(const uintx4*)(P + (size_t)d * 32 + t * 8));   // self term

    const int* cl = cols[local];
    int i = 0;
    for (; i + 8 <= dg; i += 8) {        // 8 gathers in flight
        uintx4 v[8];
#pragma unroll
        for (int u = 0; u < 8; u++)
            v[u] = *(const uintx4*)(P + (size_t)cl[i + u] * 32 + t * 8);
#pragma unroll
        for (int u = 0; u < 8; u++) add8(acc, v[u]);
    }
    if (i + 4 <= dg) {
        uintx4 v0 = *(const uintx4*)(P + (size_t)cl[i] * 32 + t * 8);
        uintx4 v1 = *(const uintx4*)(P + (size_t)cl[i + 1] * 32 + t * 8);
        uintx4 v2 = *(const uintx4*)(P + (size_t)cl[i + 2] * 32 + t * 8);
        uintx4 v3 = *(const uintx4*)(P + (size_t)cl[i + 3] * 32 + t * 8);
        add8(acc, v0); add8(acc, v1); add8(acc, v2); add8(acc, v3);
        i += 4;
    }
    for (; i < dg; i++)
        add8(acc, *(const uintx4*)(P + (size_t)cl[i] * 32 + t * 8));

    float dv = dinv[d];
    float o[8];
#pragma unroll
    for (int j = 0; j < 8; j++) o[j] = acc[j] * dv;
    if (mode == 0) {
#pragma unroll
        for (int j = 0; j < 8; j++) {
            float v = o[j] + b[plane * 32 + t * 8 + j];
            float u2 = 0.7978845608028654f * (v + 0.044715f * v * v * v);
            o[j] = 0.5f * v * (1.0f + tanhf(u2)) * dv;   // pre-scale for next layer
        }
    }
    __half2 hh[4];
#pragma unroll
    for (int j = 0; j < 4; j++) hh[j] = __floats2half2_rn(o[2 * j], o[2 * j + 1]);
    uintx4 pack;
#pragma unroll
    for (int j = 0; j < 4; j++) pack[j] = *(unsigned int*)&hh[j];
    // nontemporal store: output stream must not evict this XCD's resident plane
    __builtin_nontemporal_store(pack,
        (uintx4*)(OUT + (size_t)plane * PSTRIDE + (size_t)d * 32 + t * 8));
}

// ---------------- fused segmented mean-pool + final GEMM (batch is SORTED) ----------------

__global__ __launch_bounds__(256) void k_pool_out(const __half* __restrict__ A,
                                                  const int* __restrict__ batch,
                                                  const float* __restrict__ W3,
                                                  const float* __restrict__ b3,
                                                  float* __restrict__ out) {
    int g = blockIdx.x;
    int lo = 0, hi = N_NODES;
    while (lo < hi) { int m = (lo + hi) >> 1; if (batch[m] < g) lo = m + 1; else hi = m; }
    int lo2 = lo, hi2 = N_NODES;
    while (lo2 < hi2) { int m = (lo2 + hi2) >> 1; if (batch[m] < g + 1) lo2 = m + 1; else hi2 = m; }
    int start = lo, end = lo2;

    int lane = threadIdx.x & 63;
    int wave = threadIdx.x >> 6;
    const __half* Ap = A + (size_t)(lane >> 5) * PSTRIDE + (lane & 31);
    float acc = 0.f;
    for (int n = start + wave; n < end; n += 4)
        acc += __half2float(Ap[(size_t)n * 32]);

    __shared__ float part[4][HID];
    __shared__ float pooled[HID];
    part[wave][lane] = acc;
    __syncthreads();
    if (threadIdx.x < HID)
        pooled[threadIdx.x] = part[0][threadIdx.x] + part[1][threadIdx.x] +
                              part[2][threadIdx.x] + part[3][threadIdx.x];
    __syncthreads();

    if (threadIdx.x < OUT_DIM) {
        float cntf = (float)(end - start);
        float inv = 1.0f / fmaxf(cntf, 1.0f);
        float s = 0.f;
#pragma unroll
        for (int k = 0; k < HID; k++) s += pooled[k] * W3[k * OUT_DIM + threadIdx.x];
        out[g * OUT_DIM + threadIdx.x] = (s + cntf * b3[threadIdx.x]) * inv;
    }
}

// ---------------- launch ----------------

extern "C" void kernel_launch(void* const* d_in, const int* in_sizes, int n_in,
                              void* d_out, int out_size, void* d_ws, size_t ws_size,
                              hipStream_t stream) {
    const float* x     = (const float*)d_in[0];
    const int*   ei    = (const int*)d_in[1];
    const int*   batch = (const int*)d_in[2];
    const float* W1    = (const float*)d_in[4];
    const float* b1    = (const float*)d_in[5];
    const float* W2    = (const float*)d_in[6];
    const float* b2    = (const float*)d_in[7];
    const float* W3    = (const float*)d_in[8];
    const float* b3    = (const float*)d_in[9];
    float* out = (float*)d_out;

    const int* esrc = ei;
    const int* edst = ei + N_EDGES;

    // workspace layout
    int*    deg  = (int*)d_ws;                           // 50000 (zeroed; doubles as cursor)
    float*  dinv = (float*)(deg + N_NODES);              // 50000
    int*    col  = (int*)(dinv + N_NODES);               // 3.2M ints (12.8 MB)
    __half* t    = (__half*)(col + (size_t)N_NODES * MAX_DEG);   // 3.2M halves (2 planes)
    __half* p    = t + 2 * PSTRIDE;                              // 3.2M halves (2 planes)
    __half* Wt1  = p + 2 * PSTRIDE;                              // 8192 halves
    __half* Wt2  = Wt1 + IN_DIM * HID;                           // 4096 halves

    (void)hipMemsetAsync(deg, 0, (size_t)N_NODES * 4, stream);

    const int CHUNKS = (N_EDGES + EPB - 1) / EPB;        // 196
    k_build<<<CHUNKS * PARTS, 256, 0, stream>>>(esrc, edst, deg, col);
    k_prep<<<202, 256, 0, stream>>>(deg, dinv, W1, Wt1, W2, Wt2);

    const int GB = (N_NODES + 63) / 64;                  // 782 MFMA blocks
    const int AB = 2 * ((N_NODES + AGG_NPB - 1) / AGG_NPB);   // 2 planes x 782 agg blocks

    // layer 1 (x-cvt + dinv pre-scale fused into MFMA A-load)
    k_mfma1<<<GB, 256, 0, stream>>>(x, dinv, Wt1, t);
    k_agg<<<AB, 256, 0, stream>>>(t, col, deg, dinv, b1, p, 0);
    // layer 2
    k_mfma2<<<GB, 256, 0, stream>>>(p, Wt2, t);
    k_agg<<<AB, 256, 0, stream>>>(t, col, deg, dinv, b2, p, 0);
    // layer 3 aggregate (width 64, pre-GEMM)
    k_agg<<<AB, 256, 0, stream>>>(p, col, deg, dinv, b3, t, 1);
    // fused mean-pool + 64->128 GEMM
    k_pool_out<<<N_GRAPHS, 256, 0, stream>>>(t, batch, W3, b3, out);
}

// Round 4
// 218.476 us; speedup vs baseline: 1.2447x; 1.2447x over previous
//
#include <hip/hip_runtime.h>
#include <hip/hip_fp16.h>
#include <math.h>

#define N_NODES   50000
#define N_EDGES   800000
#define IN_DIM    128
#define HID       64
#define OUT_DIM   128
#define N_GRAPHS  256
#define MAX_DEG   64      // ELL row stride; P(indeg>64) for Binomial(800k,1/50k) ~ 0
#define PARTS     8       // XCD count; blockIdx%8 -> XCD round-robin heuristic
#define PSIZE     (N_NODES / PARTS)
#define EPB       4096    // edges per build chunk (= 256 threads x 16 edges)
#define AGG_NPB   32      // nodes per agg block (4 waves x 8 octets)

typedef _Float16 half8 __attribute__((ext_vector_type(8)));
typedef float floatx4 __attribute__((ext_vector_type(4)));

// ---------------- preprocessing ----------------

// XCD-partitioned histogram + ELL fill.
// R6: force MLP — batch-load 16 edges via int4, atomic pass, then store pass.
// (serial version compiled to VGPR=4: fully serialized load->atomic->store chain)
__global__ __launch_bounds__(256) void k_build(const int* __restrict__ src,
                                               const int* __restrict__ dst,
                                               int* __restrict__ deg, int* __restrict__ col) {
    int p     = blockIdx.x & (PARTS - 1);
    int chunk = blockIdx.x >> 3;
    int e0    = chunk * EPB + threadIdx.x * 16;
    if (e0 + 16 > N_EDGES) return;        // tail chunk is 1280 = 80*16 edges: clean cut
    int lo = p * PSIZE, hi = lo + PSIZE;

    int dd[16], ss[16];
    const int4* d4 = (const int4*)(dst + e0);
    const int4* s4 = (const int4*)(src + e0);
#pragma unroll
    for (int j = 0; j < 4; j++) {
        int4 q = d4[j];
        dd[4 * j + 0] = q.x; dd[4 * j + 1] = q.y;
        dd[4 * j + 2] = q.z; dd[4 * j + 3] = q.w;
    }
#pragma unroll
    for (int j = 0; j < 4; j++) {
        int4 q = s4[j];
        ss[4 * j + 0] = q.x; ss[4 * j + 1] = q.y;
        ss[4 * j + 2] = q.z; ss[4 * j + 3] = q.w;
    }

    // phase 1: issue all matching atomics back-to-back (independent chains)
    int pos[16];
#pragma unroll
    for (int j = 0; j < 16; j++) {
        pos[j] = -1;
        if (dd[j] >= lo && dd[j] < hi) pos[j] = atomicAdd(&deg[dd[j]], 1);
    }
    // phase 2: scatter stores (each waits only on its own atomic return)
#pragma unroll
    for (int j = 0; j < 16; j++) {
        if (pos[j] >= 0 && pos[j] < MAX_DEG)
            col[(size_t)dd[j] * MAX_DEG + pos[j]] = ss[j];
    }
}

// merged: dinv (blocks 0..195) + pack W1 (196..199) + pack W2 (200..201)
__global__ __launch_bounds__(256) void k_prep(const int* __restrict__ deg,
                                              float* __restrict__ dinv,
                                              const float* __restrict__ W1, __half* __restrict__ Wt1,
                                              const float* __restrict__ W2, __half* __restrict__ Wt2) {
    int blk = blockIdx.x;
    if (blk < 196) {
        int n = blk * 256 + threadIdx.x;
        if (n < N_NODES) dinv[n] = rsqrtf((float)(deg[n] + 1));  // +1 self-loop
    } else if (blk < 200) {
        int idx = (blk - 196) * 256 + threadIdx.x;   // 0..1023 = (128/8)*64
        int g = idx >> 6, n = idx & 63;
#pragma unroll
        for (int i = 0; i < 8; i++)
            Wt1[idx * 8 + i] = __float2half(W1[(8 * g + i) * 64 + n]);
    } else {
        int idx = (blk - 200) * 256 + threadIdx.x;   // 0..511 = (64/8)*64
        if (idx < 512) {
            int g = idx >> 6, n = idx & 63;
#pragma unroll
            for (int i = 0; i < 8; i++)
                Wt2[idx * 8 + i] = __float2half(W2[(8 * g + i) * 64 + n]);
        }
    }
}

// ---------------- MFMA GEMM layer 1: C = (dinv ⊙ x_fp32) @ W1, cvt fused ----------------

__global__ __launch_bounds__(256) void k_mfma1(const float* __restrict__ A,
                                               const float* __restrict__ dinv,
                                               const __half* __restrict__ Bp,
                                               __half* __restrict__ C) {
    constexpr int K = IN_DIM, S = K / 32;
    int wv   = threadIdx.x >> 6;
    int lane = threadIdx.x & 63;
    int quad = lane >> 4, l15 = lane & 15;
    int row0 = blockIdx.x * 64 + wv * 16;
    if (row0 >= N_NODES) return;   // 50000 % 16 == 0

    half8 bf[S][4];
#pragma unroll
    for (int s = 0; s < S; s++)
#pragma unroll
        for (int j = 0; j < 4; j++)
            bf[s][j] = *(const half8*)(Bp + ((size_t)((4 * s + quad) * 64 + 16 * j + l15)) * 8);

    floatx4 acc[4];
#pragma unroll
    for (int j = 0; j < 4; j++) acc[j] = 0.f;

    int arow = row0 + l15;
    float dv = dinv[arow];
#pragma unroll
    for (int s = 0; s < S; s++) {
        float4 xa = *(const float4*)(A + (size_t)arow * K + 32 * s + quad * 8);
        float4 xb = *(const float4*)(A + (size_t)arow * K + 32 * s + quad * 8 + 4);
        half8 af;
        af[0] = (_Float16)(xa.x * dv); af[1] = (_Float16)(xa.y * dv);
        af[2] = (_Float16)(xa.z * dv); af[3] = (_Float16)(xa.w * dv);
        af[4] = (_Float16)(xb.x * dv); af[5] = (_Float16)(xb.y * dv);
        af[6] = (_Float16)(xb.z * dv); af[7] = (_Float16)(xb.w * dv);
#pragma unroll
        for (int j = 0; j < 4; j++)
            acc[j] = __builtin_amdgcn_mfma_f32_16x16x32_f16(af, bf[s][j], acc[j], 0, 0, 0);
    }
#pragma unroll
    for (int j = 0; j < 4; j++)
#pragma unroll
        for (int r = 0; r < 4; r++)
            C[(size_t)(row0 + quad * 4 + r) * 64 + 16 * j + l15] = __float2half(acc[j][r]);
}

// ---------------- MFMA GEMM layer 2: fp16 A ----------------

__global__ __launch_bounds__(256) void k_mfma2(const __half* __restrict__ A,
                                               const __half* __restrict__ Bp,
                                               __half* __restrict__ C) {
    constexpr int K = HID, S = K / 32;
    int wv   = threadIdx.x >> 6;
    int lane = threadIdx.x & 63;
    int quad = lane >> 4, l15 = lane & 15;
    int row0 = blockIdx.x * 64 + wv * 16;
    if (row0 >= N_NODES) return;

    half8 bf[S][4];
#pragma unroll
    for (int s = 0; s < S; s++)
#pragma unroll
        for (int j = 0; j < 4; j++)
            bf[s][j] = *(const half8*)(Bp + ((size_t)((4 * s + quad) * 64 + 16 * j + l15)) * 8);

    floatx4 acc[4];
#pragma unroll
    for (int j = 0; j < 4; j++) acc[j] = 0.f;

    int arow = row0 + l15;
#pragma unroll
    for (int s = 0; s < S; s++) {
        half8 af = *(const half8*)(A + (size_t)arow * K + 32 * s + quad * 8);
#pragma unroll
        for (int j = 0; j < 4; j++)
            acc[j] = __builtin_amdgcn_mfma_f32_16x16x32_f16(af, bf[s][j], acc[j], 0, 0, 0);
    }
#pragma unroll
    for (int j = 0; j < 4; j++)
#pragma unroll
        for (int r = 0; r < 4; r++)
            C[(size_t)(row0 + quad * 4 + r) * 64 + 16 * j + l15] = __float2half(acc[j][r]);
}

// ---------------- aggregation (R0 structure + deg-limited staging only) ----------------
// mode 0: OUT = dinv * gelu_tanh( dinv*(Σ_in T[s] + T[d]) + b )   (pre-scaled for next layer)
// mode 1: OUT = dinv * (Σ_in T[s] + T[d])

__device__ __forceinline__ void add8(float* acc, uint4 v) {
    const __half2* h = (const __half2*)&v;
#pragma unroll
    for (int j = 0; j < 4; j++) {
        acc[2 * j]     += __low2float(h[j]);
        acc[2 * j + 1] += __high2float(h[j]);
    }
}

__global__ __launch_bounds__(256) void k_agg(const __half* __restrict__ T,
                                             const int* __restrict__ col,
                                             const int* __restrict__ indeg,
                                             const float* __restrict__ dinv,
                                             const float* __restrict__ b,
                                             __half* __restrict__ OUT, int mode) {
    __shared__ int cols[AGG_NPB][MAX_DEG + 1];   // +1 pad: octets land in distinct banks
    __shared__ int sdeg[AGG_NPB];
    int base = blockIdx.x * AGG_NPB;

    if (threadIdx.x < AGG_NPB) {
        int g = base + threadIdx.x;
        int dg0 = (g < N_NODES) ? indeg[g] : 0;
        sdeg[threadIdx.x] = dg0 > MAX_DEG ? MAX_DEG : dg0;
    }
    __syncthreads();

    // stage only live ELL slots (mean deg ~16 of 64 -> ~75% fewer col reads)
    for (int idx = threadIdx.x; idx < AGG_NPB * MAX_DEG; idx += 256) {
        int r = idx >> 6, j = idx & 63;
        if (j < sdeg[r]) cols[r][j] = col[(size_t)(base + r) * MAX_DEG + j];
    }
    __syncthreads();

    int lane = threadIdx.x & 63;
    int wv   = threadIdx.x >> 6;
    int q = lane >> 3, t = lane & 7;     // octet = node, t = 16-byte chunk
    int local = wv * 8 + q;
    int d = base + local;
    if (d >= N_NODES) return;            // tail block: whole octets drop out

    int dg = sdeg[local];

    float acc[8];
#pragma unroll
    for (int j = 0; j < 8; j++) acc[j] = 0.f;
    add8(acc, *(const uint4*)(T + (size_t)d * HID + t * 8));   // self term

    const int* cl = cols[local];
    int i = 0;
    for (; i + 4 <= dg; i += 4) {
        int s0 = cl[i], s1 = cl[i + 1], s2 = cl[i + 2], s3 = cl[i + 3];
        uint4 v0 = *(const uint4*)(T + (size_t)s0 * HID + t * 8);
        uint4 v1 = *(const uint4*)(T + (size_t)s1 * HID + t * 8);
        uint4 v2 = *(const uint4*)(T + (size_t)s2 * HID + t * 8);
        uint4 v3 = *(const uint4*)(T + (size_t)s3 * HID + t * 8);
        add8(acc, v0); add8(acc, v1); add8(acc, v2); add8(acc, v3);
    }
    for (; i < dg; i++) {
        int s = cl[i];
        add8(acc, *(const uint4*)(T + (size_t)s * HID + t * 8));
    }

    float dv = dinv[d];
    float o[8];
#pragma unroll
    for (int j = 0; j < 8; j++) o[j] = acc[j] * dv;
    if (mode == 0) {
#pragma unroll
        for (int j = 0; j < 8; j++) {
            float v = o[j] + b[t * 8 + j];
            float u2 = 0.7978845608028654f * (v + 0.044715f * v * v * v);
            o[j] = 0.5f * v * (1.0f + tanhf(u2)) * dv;   // pre-scale for next layer
        }
    }
    __half2 hh[4];
#pragma unroll
    for (int j = 0; j < 4; j++) hh[j] = __floats2half2_rn(o[2 * j], o[2 * j + 1]);
    *(uint4*)(OUT + (size_t)d * HID + t * 8) = *(uint4*)hh;
}

// ---------------- fused segmented mean-pool + final GEMM (batch is SORTED) ----------------

__global__ __launch_bounds__(256) void k_pool_out(const __half* __restrict__ A,
                                                  const int* __restrict__ batch,
                                                  const float* __restrict__ W3,
                                                  const float* __restrict__ b3,
                                                  float* __restrict__ out) {
    int g = blockIdx.x;
    int lo = 0, hi = N_NODES;
    while (lo < hi) { int m = (lo + hi) >> 1; if (batch[m] < g) lo = m + 1; else hi = m; }
    int lo2 = lo, hi2 = N_NODES;
    while (lo2 < hi2) { int m = (lo2 + hi2) >> 1; if (batch[m] < g + 1) lo2 = m + 1; else hi2 = m; }
    int start = lo, end = lo2;

    int lane = threadIdx.x & 63;
    int wave = threadIdx.x >> 6;
    float acc = 0.f;
    for (int n = start + wave; n < end; n += 4)
        acc += __half2float(A[(size_t)n * HID + lane]);

    __shared__ float part[4][HID];
    __shared__ float pooled[HID];
    part[wave][lane] = acc;
    __syncthreads();
    if (threadIdx.x < HID)
        pooled[threadIdx.x] = part[0][threadIdx.x] + part[1][threadIdx.x] +
                              part[2][threadIdx.x] + part[3][threadIdx.x];
    __syncthreads();

    if (threadIdx.x < OUT_DIM) {
        float cntf = (float)(end - start);
        float inv = 1.0f / fmaxf(cntf, 1.0f);
        float s = 0.f;
#pragma unroll
        for (int k = 0; k < HID; k++) s += pooled[k] * W3[k * OUT_DIM + threadIdx.x];
        out[g * OUT_DIM + threadIdx.x] = (s + cntf * b3[threadIdx.x]) * inv;
    }
}

// ---------------- launch ----------------

extern "C" void kernel_launch(void* const* d_in, const int* in_sizes, int n_in,
                              void* d_out, int out_size, void* d_ws, size_t ws_size,
                              hipStream_t stream) {
    const float* x     = (const float*)d_in[0];
    const int*   ei    = (const int*)d_in[1];
    const int*   batch = (const int*)d_in[2];
    const float* W1    = (const float*)d_in[4];
    const float* b1    = (const float*)d_in[5];
    const float* W2    = (const float*)d_in[6];
    const float* b2    = (const float*)d_in[7];
    const float* W3    = (const float*)d_in[8];
    const float* b3    = (const float*)d_in[9];
    float* out = (float*)d_out;

    const int* esrc = ei;
    const int* edst = ei + N_EDGES;

    // workspace layout
    int*    deg  = (int*)d_ws;                           // 50000 (zeroed; doubles as cursor)
    float*  dinv = (float*)(deg + N_NODES);              // 50000
    int*    col  = (int*)(dinv + N_NODES);               // 3.2M ints (12.8 MB)
    __half* t    = (__half*)(col + (size_t)N_NODES * MAX_DEG);   // 3.2M halves
    __half* p    = t + (size_t)N_NODES * HID;                    // 3.2M halves
    __half* Wt1  = p + (size_t)N_NODES * HID;                    // 8192 halves
    __half* Wt2  = Wt1 + IN_DIM * HID;                           // 4096 halves

    (void)hipMemsetAsync(deg, 0, (size_t)N_NODES * 4, stream);

    const int CHUNKS = (N_EDGES + EPB - 1) / EPB;        // 196
    k_build<<<CHUNKS * PARTS, 256, 0, stream>>>(esrc, edst, deg, col);
    k_prep<<<202, 256, 0, stream>>>(deg, dinv, W1, Wt1, W2, Wt2);

    const int GB = (N_NODES + 63) / 64;        // 782 MFMA blocks
    const int AB = (N_NODES + AGG_NPB - 1) / AGG_NPB;   // 1563 agg blocks

    // layer 1 (x-cvt + dinv pre-scale fused into MFMA A-load)
    k_mfma1<<<GB, 256, 0, stream>>>(x, dinv, Wt1, t);
    k_agg<<<AB, 256, 0, stream>>>(t, col, deg, dinv, b1, p, 0);
    // layer 2
    k_mfma2<<<GB, 256, 0, stream>>>(p, Wt2, t);
    k_agg<<<AB, 256, 0, stream>>>(t, col, deg, dinv, b2, p, 0);
    // layer 3 aggregate (width 64, pre-GEMM)
    k_agg<<<AB, 256, 0, stream>>>(p, col, deg, dinv, b3, t, 1);
    // fused mean-pool + 64->128 GEMM
    k_pool_out<<<N_GRAPHS, 256, 0, stream>>>(t, batch, W3, b3, out);
}

// Round 5
// 215.012 us; speedup vs baseline: 1.2647x; 1.0161x over previous
//
#include <hip/hip_runtime.h>
#include <hip/hip_fp16.h>
#include <math.h>

#define N_NODES   50000
#define N_EDGES   800000
#define IN_DIM    128
#define HID       64
#define OUT_DIM   128
#define N_GRAPHS  256
#define MAX_DEG   64      // ELL row stride; P(indeg>64) for Binomial(800k,1/50k) ~ 0
#define PARTS     8       // XCD count; blockIdx%8 -> XCD round-robin heuristic
#define PSIZE     (N_NODES / PARTS)
#define EPB       4096    // edges per build chunk (= 256 threads x 16 edges)
#define AGG_NPB   32      // nodes per agg block (4 waves x 8 octets)
#define DEGP      32      // padded counter stride (ints): 1 counter per 128B line

typedef _Float16 half8 __attribute__((ext_vector_type(8)));
typedef float floatx4 __attribute__((ext_vector_type(4)));

// ---------------- preprocessing ----------------

// XCD-partitioned histogram + ELL fill. Counters padded to one per 128B L2/L3 line:
// device-scope atomics execute memory-side; 16-32 counters/line caused ~256-512
// serialized line-locked RMWs per line (theory for k_build's ILP-insensitive 40us).
__global__ __launch_bounds__(256) void k_build(const int* __restrict__ src,
                                               const int* __restrict__ dst,
                                               int* __restrict__ deg, int* __restrict__ col) {
    int p     = blockIdx.x & (PARTS - 1);
    int chunk = blockIdx.x >> 3;
    int e0    = chunk * EPB + threadIdx.x * 16;
    if (e0 + 16 > N_EDGES) return;        // tail chunk is 1280 = 80*16 edges: clean cut
    int lo = p * PSIZE, hi = lo + PSIZE;

    int dd[16], ss[16];
    const int4* d4 = (const int4*)(dst + e0);
    const int4* s4 = (const int4*)(src + e0);
#pragma unroll
    for (int j = 0; j < 4; j++) {
        int4 q = d4[j];
        dd[4 * j + 0] = q.x; dd[4 * j + 1] = q.y;
        dd[4 * j + 2] = q.z; dd[4 * j + 3] = q.w;
    }
#pragma unroll
    for (int j = 0; j < 4; j++) {
        int4 q = s4[j];
        ss[4 * j + 0] = q.x; ss[4 * j + 1] = q.y;
        ss[4 * j + 2] = q.z; ss[4 * j + 3] = q.w;
    }

    // phase 1: issue all matching atomics back-to-back (independent chains)
    int pos[16];
#pragma unroll
    for (int j = 0; j < 16; j++) {
        pos[j] = -1;
        if (dd[j] >= lo && dd[j] < hi) pos[j] = atomicAdd(&deg[(size_t)dd[j] * DEGP], 1);
    }
    // phase 2: scatter stores (each waits only on its own atomic return)
#pragma unroll
    for (int j = 0; j < 16; j++) {
        if (pos[j] >= 0 && pos[j] < MAX_DEG)
            col[(size_t)dd[j] * MAX_DEG + pos[j]] = ss[j];
    }
}

// merged: dinv + compact deg (blocks 0..195) + pack W1 (196..199) + pack W2 (200..201)
__global__ __launch_bounds__(256) void k_prep(const int* __restrict__ deg,
                                              int* __restrict__ degc,
                                              float* __restrict__ dinv,
                                              const float* __restrict__ W1, __half* __restrict__ Wt1,
                                              const float* __restrict__ W2, __half* __restrict__ Wt2) {
    int blk = blockIdx.x;
    if (blk < 196) {
        int n = blk * 256 + threadIdx.x;
        if (n < N_NODES) {
            int dg = deg[(size_t)n * DEGP];
            degc[n] = dg;
            dinv[n] = rsqrtf((float)(dg + 1));  // +1 self-loop
        }
    } else if (blk < 200) {
        int idx = (blk - 196) * 256 + threadIdx.x;   // 0..1023 = (128/8)*64
        int g = idx >> 6, n = idx & 63;
#pragma unroll
        for (int i = 0; i < 8; i++)
            Wt1[idx * 8 + i] = __float2half(W1[(8 * g + i) * 64 + n]);
    } else {
        int idx = (blk - 200) * 256 + threadIdx.x;   // 0..511 = (64/8)*64
        if (idx < 512) {
            int g = idx >> 6, n = idx & 63;
#pragma unroll
            for (int i = 0; i < 8; i++)
                Wt2[idx * 8 + i] = __float2half(W2[(8 * g + i) * 64 + n]);
        }
    }
}

// ---------------- MFMA GEMM layer 1: C = (dinv ⊙ x_fp32) @ W1, cvt fused ----------------

__global__ __launch_bounds__(256) void k_mfma1(const float* __restrict__ A,
                                               const float* __restrict__ dinv,
                                               const __half* __restrict__ Bp,
                                               __half* __restrict__ C) {
    constexpr int K = IN_DIM, S = K / 32;
    int wv   = threadIdx.x >> 6;
    int lane = threadIdx.x & 63;
    int quad = lane >> 4, l15 = lane & 15;
    int row0 = blockIdx.x * 64 + wv * 16;
    if (row0 >= N_NODES) return;   // 50000 % 16 == 0

    half8 bf[S][4];
#pragma unroll
    for (int s = 0; s < S; s++)
#pragma unroll
        for (int j = 0; j < 4; j++)
            bf[s][j] = *(const half8*)(Bp + ((size_t)((4 * s + quad) * 64 + 16 * j + l15)) * 8);

    floatx4 acc[4];
#pragma unroll
    for (int j = 0; j < 4; j++) acc[j] = 0.f;

    int arow = row0 + l15;
    float dv = dinv[arow];
#pragma unroll
    for (int s = 0; s < S; s++) {
        float4 xa = *(const float4*)(A + (size_t)arow * K + 32 * s + quad * 8);
        float4 xb = *(const float4*)(A + (size_t)arow * K + 32 * s + quad * 8 + 4);
        half8 af;
        af[0] = (_Float16)(xa.x * dv); af[1] = (_Float16)(xa.y * dv);
        af[2] = (_Float16)(xa.z * dv); af[3] = (_Float16)(xa.w * dv);
        af[4] = (_Float16)(xb.x * dv); af[5] = (_Float16)(xb.y * dv);
        af[6] = (_Float16)(xb.z * dv); af[7] = (_Float16)(xb.w * dv);
#pragma unroll
        for (int j = 0; j < 4; j++)
            acc[j] = __builtin_amdgcn_mfma_f32_16x16x32_f16(af, bf[s][j], acc[j], 0, 0, 0);
    }
#pragma unroll
    for (int j = 0; j < 4; j++)
#pragma unroll
        for (int r = 0; r < 4; r++)
            C[(size_t)(row0 + quad * 4 + r) * 64 + 16 * j + l15] = __float2half(acc[j][r]);
}

// ---------------- MFMA GEMM layer 2: fp16 A ----------------

__global__ __launch_bounds__(256) void k_mfma2(const __half* __restrict__ A,
                                               const __half* __restrict__ Bp,
                                               __half* __restrict__ C) {
    constexpr int K = HID, S = K / 32;
    int wv   = threadIdx.x >> 6;
    int lane = threadIdx.x & 63;
    int quad = lane >> 4, l15 = lane & 15;
    int row0 = blockIdx.x * 64 + wv * 16;
    if (row0 >= N_NODES) return;

    half8 bf[S][4];
#pragma unroll
    for (int s = 0; s < S; s++)
#pragma unroll
        for (int j = 0; j < 4; j++)
            bf[s][j] = *(const half8*)(Bp + ((size_t)((4 * s + quad) * 64 + 16 * j + l15)) * 8);

    floatx4 acc[4];
#pragma unroll
    for (int j = 0; j < 4; j++) acc[j] = 0.f;

    int arow = row0 + l15;
#pragma unroll
    for (int s = 0; s < S; s++) {
        half8 af = *(const half8*)(A + (size_t)arow * K + 32 * s + quad * 8);
#pragma unroll
        for (int j = 0; j < 4; j++)
            acc[j] = __builtin_amdgcn_mfma_f32_16x16x32_f16(af, bf[s][j], acc[j], 0, 0, 0);
    }
#pragma unroll
    for (int j = 0; j < 4; j++)
#pragma unroll
        for (int r = 0; r < 4; r++)
            C[(size_t)(row0 + quad * 4 + r) * 64 + 16 * j + l15] = __float2half(acc[j][r]);
}

// ---------------- aggregation (R0 structure + deg-limited staging) ----------------
// mode 0: OUT = dinv * gelu_tanh( dinv*(Σ_in T[s] + T[d]) + b )   (pre-scaled for next layer)
// mode 1: OUT = dinv * (Σ_in T[s] + T[d])

__device__ __forceinline__ void add8(float* acc, uint4 v) {
    const __half2* h = (const __half2*)&v;
#pragma unroll
    for (int j = 0; j < 4; j++) {
        acc[2 * j]     += __low2float(h[j]);
        acc[2 * j + 1] += __high2float(h[j]);
    }
}

__global__ __launch_bounds__(256) void k_agg(const __half* __restrict__ T,
                                             const int* __restrict__ col,
                                             const int* __restrict__ indeg,
                                             const float* __restrict__ dinv,
                                             const float* __restrict__ b,
                                             __half* __restrict__ OUT, int mode) {
    __shared__ int cols[AGG_NPB][MAX_DEG + 1];   // +1 pad: octets land in distinct banks
    __shared__ int sdeg[AGG_NPB];
    int base = blockIdx.x * AGG_NPB;

    if (threadIdx.x < AGG_NPB) {
        int g = base + threadIdx.x;
        int dg0 = (g < N_NODES) ? indeg[g] : 0;
        sdeg[threadIdx.x] = dg0 > MAX_DEG ? MAX_DEG : dg0;
    }
    __syncthreads();

    // stage only live ELL slots (mean deg ~16 of 64 -> ~75% fewer col reads)
    for (int idx = threadIdx.x; idx < AGG_NPB * MAX_DEG; idx += 256) {
        int r = idx >> 6, j = idx & 63;
        if (j < sdeg[r]) cols[r][j] = col[(size_t)(base + r) * MAX_DEG + j];
    }
    __syncthreads();

    int lane = threadIdx.x & 63;
    int wv   = threadIdx.x >> 6;
    int q = lane >> 3, t = lane & 7;     // octet = node, t = 16-byte chunk
    int local = wv * 8 + q;
    int d = base + local;
    if (d >= N_NODES) return;            // tail block: whole octets drop out

    int dg = sdeg[local];

    float acc[8];
#pragma unroll
    for (int j = 0; j < 8; j++) acc[j] = 0.f;
    add8(acc, *(const uint4*)(T + (size_t)d * HID + t * 8));   // self term

    const int* cl = cols[local];
    int i = 0;
    for (; i + 4 <= dg; i += 4) {
        int s0 = cl[i], s1 = cl[i + 1], s2 = cl[i + 2], s3 = cl[i + 3];
        uint4 v0 = *(const uint4*)(T + (size_t)s0 * HID + t * 8);
        uint4 v1 = *(const uint4*)(T + (size_t)s1 * HID + t * 8);
        uint4 v2 = *(const uint4*)(T + (size_t)s2 * HID + t * 8);
        uint4 v3 = *(const uint4*)(T + (size_t)s3 * HID + t * 8);
        add8(acc, v0); add8(acc, v1); add8(acc, v2); add8(acc, v3);
    }
    for (; i < dg; i++) {
        int s = cl[i];
        add8(acc, *(const uint4*)(T + (size_t)s * HID + t * 8));
    }

    float dv = dinv[d];
    float o[8];
#pragma unroll
    for (int j = 0; j < 8; j++) o[j] = acc[j] * dv;
    if (mode == 0) {
#pragma unroll
        for (int j = 0; j < 8; j++) {
            float v = o[j] + b[t * 8 + j];
            float u2 = 0.7978845608028654f * (v + 0.044715f * v * v * v);
            o[j] = 0.5f * v * (1.0f + tanhf(u2)) * dv;   // pre-scale for next layer
        }
    }
    __half2 hh[4];
#pragma unroll
    for (int j = 0; j < 4; j++) hh[j] = __floats2half2_rn(o[2 * j], o[2 * j + 1]);
    *(uint4*)(OUT + (size_t)d * HID + t * 8) = *(uint4*)hh;
}

// ---------------- fused segmented mean-pool + final GEMM (batch is SORTED) ----------------

__global__ __launch_bounds__(256) void k_pool_out(const __half* __restrict__ A,
                                                  const int* __restrict__ batch,
                                                  const float* __restrict__ W3,
                                                  const float* __restrict__ b3,
                                                  float* __restrict__ out) {
    int g = blockIdx.x;
    int lo = 0, hi = N_NODES;
    while (lo < hi) { int m = (lo + hi) >> 1; if (batch[m] < g) lo = m + 1; else hi = m; }
    int lo2 = lo, hi2 = N_NODES;
    while (lo2 < hi2) { int m = (lo2 + hi2) >> 1; if (batch[m] < g + 1) lo2 = m + 1; else hi2 = m; }
    int start = lo, end = lo2;

    int lane = threadIdx.x & 63;
    int wave = threadIdx.x >> 6;
    float acc = 0.f;
    for (int n = start + wave; n < end; n += 4)
        acc += __half2float(A[(size_t)n * HID + lane]);

    __shared__ float part[4][HID];
    __shared__ float pooled[HID];
    part[wave][lane] = acc;
    __syncthreads();
    if (threadIdx.x < HID)
        pooled[threadIdx.x] = part[0][threadIdx.x] + part[1][threadIdx.x] +
                              part[2][threadIdx.x] + part[3][threadIdx.x];
    __syncthreads();

    if (threadIdx.x < OUT_DIM) {
        float cntf = (float)(end - start);
        float inv = 1.0f / fmaxf(cntf, 1.0f);
        float s = 0.f;
#pragma unroll
        for (int k = 0; k < HID; k++) s += pooled[k] * W3[k * OUT_DIM + threadIdx.x];
        out[g * OUT_DIM + threadIdx.x] = (s + cntf * b3[threadIdx.x]) * inv;
    }
}

// ---------------- launch ----------------

extern "C" void kernel_launch(void* const* d_in, const int* in_sizes, int n_in,
                              void* d_out, int out_size, void* d_ws, size_t ws_size,
                              hipStream_t stream) {
    const float* x     = (const float*)d_in[0];
    const int*   ei    = (const int*)d_in[1];
    const int*   batch = (const int*)d_in[2];
    const float* W1    = (const float*)d_in[4];
    const float* b1    = (const float*)d_in[5];
    const float* W2    = (const float*)d_in[6];
    const float* b2    = (const float*)d_in[7];
    const float* W3    = (const float*)d_in[8];
    const float* b3    = (const float*)d_in[9];
    float* out = (float*)d_out;

    const int* esrc = ei;
    const int* edst = ei + N_EDGES;

    // workspace layout
    int*    deg  = (int*)d_ws;                           // 50000 x DEGP (padded; zeroed)
    int*    degc = deg + (size_t)N_NODES * DEGP;         // 50000 compact
    float*  dinv = (float*)(degc + N_NODES);             // 50000
    int*    col  = (int*)(dinv + N_NODES);               // 3.2M ints (12.8 MB)
    __half* t    = (__half*)(col + (size_t)N_NODES * MAX_DEG);   // 3.2M halves
    __half* p    = t + (size_t)N_NODES * HID;                    // 3.2M halves
    __half* Wt1  = p + (size_t)N_NODES * HID;                    // 8192 halves
    __half* Wt2  = Wt1 + IN_DIM * HID;                           // 4096 halves

    (void)hipMemsetAsync(deg, 0, (size_t)N_NODES * DEGP * 4, stream);

    const int CHUNKS = (N_EDGES + EPB - 1) / EPB;        // 196
    k_build<<<CHUNKS * PARTS, 256, 0, stream>>>(esrc, edst, deg, col);
    k_prep<<<202, 256, 0, stream>>>(deg, degc, dinv, W1, Wt1, W2, Wt2);

    const int GB = (N_NODES + 63) / 64;        // 782 MFMA blocks
    const int AB = (N_NODES + AGG_NPB - 1) / AGG_NPB;   // 1563 agg blocks

    // layer 1 (x-cvt + dinv pre-scale fused into MFMA A-load)
    k_mfma1<<<GB, 256, 0, stream>>>(x, dinv, Wt1, t);
    k_agg<<<AB, 256, 0, stream>>>(t, col, degc, dinv, b1, p, 0);
    // layer 2
    k_mfma2<<<GB, 256, 0, stream>>>(p, Wt2, t);
    k_agg<<<AB, 256, 0, stream>>>(t, col, degc, dinv, b2, p, 0);
    // layer 3 aggregate (width 64, pre-GEMM)
    k_agg<<<AB, 256, 0, stream>>>(p, col, degc, dinv, b3, t, 1);
    // fused mean-pool + 64->128 GEMM
    k_pool_out<<<N_GRAPHS, 256, 0, stream>>>(t, batch, W3, b3, out);
}